// Round 5
// baseline (253.578 us; speedup 1.0000x reference)
//
#include <hip/hip_runtime.h>
#include <hip/hip_bf16.h>

#define D_FEAT 64
#define OVF_CAP 65536
#define EB 2048              // edges per split block (8 wave-iters of 256)
#define NSUB 128             // place blocks per range (grid = 8*NSUB)

typedef unsigned int uint32;

__device__ inline float blo(uint32 u) { return __uint_as_float(u << 16); }
__device__ inline float bhi(uint32 u) { return __uint_as_float(u & 0xffff0000u); }
__device__ inline float dinv(int d) { return (d > 0) ? rsqrtf((float)d) : 0.0f; }

// ---- pass 1: 8-way split by (col & 7) into packed segments; coalesced
//      writes via ballot ranks + one global reservation per (block,range).
//      Fused bf16 cast of x. Segment overflow -> direct scatter (exact).
__global__ __launch_bounds__(256) void k_split(const int* __restrict__ row,
                                               const int* __restrict__ col,
                                               const float2* __restrict__ x2,
                                               uint32* __restrict__ xb,
                                               uint2* __restrict__ seg,
                                               int* __restrict__ cur8,
                                               int* __restrict__ deg,
                                               int* __restrict__ slots,
                                               int2* __restrict__ ovf,
                                               int* __restrict__ ovf_cnt,
                                               int nhalf, int E, int CAPR, int C) {
    __shared__ int wcnt[4][8];
    __shared__ int wbase[4][8];
    const int wv = threadIdx.x >> 6;
    const int lane = threadIdx.x & 63;
    const unsigned long long mlt = ((unsigned long long)1 << lane) - 1;
    const int s = blockIdx.x * EB;

    // count phase (per-wave, ballot-aggregated)
    int cnt[8] = {0, 0, 0, 0, 0, 0, 0, 0};
#pragma unroll
    for (int it = 0; it < EB / 256; ++it) {
        int i = s + it * 256 + wv * 64 + lane;
        int b = 8;
        if (i < E) b = col[i] & 7;
#pragma unroll
        for (int k = 0; k < 8; ++k)
            cnt[k] += __popcll(__ballot(b == k));
    }
    if (lane == 0) {
#pragma unroll
        for (int k = 0; k < 8; ++k) wcnt[wv][k] = cnt[k];
    }
    __syncthreads();
    if (threadIdx.x < 8) {
        int k = threadIdx.x;
        int t0 = wcnt[0][k], t1 = wcnt[1][k], t2 = wcnt[2][k], t3 = wcnt[3][k];
        int tot = t0 + t1 + t2 + t3;
        int g = tot ? atomicAdd(&cur8[k], tot) : 0;
        wbase[0][k] = g;
        wbase[1][k] = g + t0;
        wbase[2][k] = g + t0 + t1;
        wbase[3][k] = g + t0 + t1 + t2;
    }
    __syncthreads();

    // placement phase (identical iteration order)
    int run[8];
#pragma unroll
    for (int k = 0; k < 8; ++k) run[k] = wbase[wv][k];
#pragma unroll
    for (int it = 0; it < EB / 256; ++it) {
        int i = s + it * 256 + wv * 64 + lane;
        int b = 8, c = 0, r = 0;
        if (i < E) { c = col[i]; r = row[i]; b = c & 7; }
#pragma unroll
        for (int k = 0; k < 8; ++k) {
            unsigned long long m = __ballot(b == k);
            if (b == k) {
                int pos = run[k] + __popcll(m & mlt);
                if (pos < CAPR) {
                    seg[(size_t)k * CAPR + pos] = make_uint2((uint32)r, (uint32)c);
                } else {
                    // segment full: exact direct scatter (round-4 style)
                    int rk = atomicAdd(&deg[c], 1);
                    if (rk < C) {
                        slots[(size_t)c * C + rk] = r;
                    } else {
                        int o = atomicAdd(ovf_cnt, 1);
                        if (o < OVF_CAP) ovf[o] = make_int2(r, c);
                    }
                }
            }
            run[k] += __popcll(m);
        }
    }

    // fused bf16 cast, node-major linear (xb[node] = 32 contiguous uint32)
    const int t = blockIdx.x * 256 + threadIdx.x;
    const int stride = gridDim.x * 256;
    for (int j = t; j < nhalf; j += stride) {
        float2 v = x2[j];
        __hip_bfloat16 bx = __float2bfloat16(v.x);
        __hip_bfloat16 by = __float2bfloat16(v.y);
        uint32 ux = *reinterpret_cast<unsigned short*>(&bx);
        uint32 uy = *reinterpret_cast<unsigned short*>(&by);
        xb[j] = ux | (uy << 16);
    }
}

// ---- pass 2: XCD-affine scatter. range = blockIdx&7 -> with round-robin
//      dispatch, all blocks of range r sit on XCD r; slot window for range r
//      (every 8th 128B node row, 1.6MB) accumulates in that XCD's L2.
__global__ __launch_bounds__(256) void k_place(const uint2* __restrict__ seg,
                                               const int* __restrict__ cur8,
                                               int* __restrict__ deg,
                                               int* __restrict__ slots,
                                               int2* __restrict__ ovf,
                                               int* __restrict__ ovf_cnt,
                                               int CAPR, int C) {
    const int rge = blockIdx.x & 7;
    const int sub = blockIdx.x >> 3;
    int cnt = cur8[rge];
    if (cnt > CAPR) cnt = CAPR;
    const uint2* sg = seg + (size_t)rge * CAPR;
    for (int i = sub * 256 + threadIdx.x; i < cnt; i += NSUB * 256) {
        uint2 p = sg[i];
        int r = (int)p.x, c = (int)p.y;
        int rk = atomicAdd(&deg[c], 1);
        if (rk < C) {
            slots[(size_t)c * C + rk] = r;
        } else {
            int o = atomicAdd(ovf_cnt, 1);
            if (o < OVF_CAP) ovf[o] = make_int2(r, c);
        }
    }
}

// ---- gather: one wave per node, 4 edges in parallel, 16-edge unroll ----
// (verified body: ~60 us, ~3.4 TB/s random-128B fetch)
__global__ void k_gather4(const uint32* __restrict__ xb,
                          const float4* __restrict__ x4,
                          const int* __restrict__ deg,
                          const int* __restrict__ slots,
                          const float* __restrict__ alpha_p,
                          const float* __restrict__ rs_p,
                          float4* __restrict__ out4, int n, int C) {
    int wid = (blockIdx.x * blockDim.x + threadIdx.x) >> 6;
    if (wid >= n) return;
    const int lane = threadIdx.x & 63;
    const int q = lane >> 4;
    const int l = lane & 15;
    int d = deg[wid];
    int e = (d < C) ? d : C;
    float4 xr = make_float4(0.f, 0.f, 0.f, 0.f);
    if (q == 0) xr = x4[(size_t)wid * 16 + l];   // hoisted residual load
    const int* sl = slots + (size_t)wid * C;
    float ax = 0.f, ay = 0.f, az = 0.f, aw = 0.f;
    int k = 0;
    for (; k + 16 <= e; k += 16) {
        int s0 = sl[k + q];
        int s1 = sl[k + 4 + q];
        int s2 = sl[k + 8 + q];
        int s3 = sl[k + 12 + q];
        int d0 = deg[s0], d1 = deg[s1], d2 = deg[s2], d3 = deg[s3];
        uint2 p0 = ((const uint2*)(xb + (size_t)s0 * 32))[l];
        uint2 p1 = ((const uint2*)(xb + (size_t)s1 * 32))[l];
        uint2 p2 = ((const uint2*)(xb + (size_t)s2 * 32))[l];
        uint2 p3 = ((const uint2*)(xb + (size_t)s3 * 32))[l];
        float w0 = dinv(d0), w1 = dinv(d1), w2 = dinv(d2), w3 = dinv(d3);
        ax = fmaf(w0, blo(p0.x), ax); ay = fmaf(w0, bhi(p0.x), ay);
        az = fmaf(w0, blo(p0.y), az); aw = fmaf(w0, bhi(p0.y), aw);
        ax = fmaf(w1, blo(p1.x), ax); ay = fmaf(w1, bhi(p1.x), ay);
        az = fmaf(w1, blo(p1.y), az); aw = fmaf(w1, bhi(p1.y), aw);
        ax = fmaf(w2, blo(p2.x), ax); ay = fmaf(w2, bhi(p2.x), ay);
        az = fmaf(w2, blo(p2.y), az); aw = fmaf(w2, bhi(p2.y), aw);
        ax = fmaf(w3, blo(p3.x), ax); ay = fmaf(w3, bhi(p3.x), ay);
        az = fmaf(w3, blo(p3.y), az); aw = fmaf(w3, bhi(p3.y), aw);
    }
    for (; k < e; k += 4) {
        int kk = k + q;
        if (kk < e) {
            int s0 = sl[kk];
            float w0 = dinv(deg[s0]);
            uint2 p0 = ((const uint2*)(xb + (size_t)s0 * 32))[l];
            ax = fmaf(w0, blo(p0.x), ax); ay = fmaf(w0, bhi(p0.x), ay);
            az = fmaf(w0, blo(p0.y), az); aw = fmaf(w0, bhi(p0.y), aw);
        }
    }
    ax += __shfl_down(ax, 32, 64); ay += __shfl_down(ay, 32, 64);
    az += __shfl_down(az, 32, 64); aw += __shfl_down(aw, 32, 64);
    ax += __shfl_down(ax, 16, 64); ay += __shfl_down(ay, 16, 64);
    az += __shfl_down(az, 16, 64); aw += __shfl_down(aw, 16, 64);
    if (q == 0) {
        float adw = (*alpha_p) * dinv(d);
        float rs  = *rs_p;
        float4 o;
        o.x = fmaf(adw, ax, rs * xr.x);
        o.y = fmaf(adw, ay, rs * xr.y);
        o.z = fmaf(adw, az, rs * xr.z);
        o.w = fmaf(adw, aw, rs * xr.w);
        out4[(size_t)wid * 16 + l] = o;
    }
}

// ---- overflow fix-up (deg>C only; rare): fp32 exact ----
__global__ void k_ovf(const int2* __restrict__ ovf, const int* __restrict__ cnt_p,
                      const float* __restrict__ x, const int* __restrict__ deg,
                      const float* __restrict__ alpha_p, float* __restrict__ out) {
    int cnt = *cnt_p;
    if (cnt > OVF_CAP) cnt = OVF_CAP;
    if (cnt <= 0) return;
    float a = *alpha_p;
    long long total = (long long)cnt * 64;
    long long stride = (long long)gridDim.x * blockDim.x;
    for (long long idx = blockIdx.x * (long long)blockDim.x + threadIdx.x;
         idx < total; idx += stride) {
        int e = (int)(idx >> 6);
        int f = (int)(idx & 63);
        int2 rc = ovf[e];
        float w = a * dinv(deg[rc.x]) * dinv(deg[rc.y]);
        atomicAdd(&out[(size_t)rc.y * D_FEAT + f], w * x[(size_t)rc.x * D_FEAT + f]);
    }
}

// ---- fallback build: one thread per edge, direct scatter (round 4) ----
__global__ __launch_bounds__(256) void k_prep(const float2* __restrict__ x2,
                                              uint32* __restrict__ xb,
                                              const int* __restrict__ row,
                                              const int* __restrict__ col,
                                              int* __restrict__ deg,
                                              int* __restrict__ slots,
                                              int2* __restrict__ ovf,
                                              int* __restrict__ ovf_cnt,
                                              int nhalf, int E, int C) {
    const int t = blockIdx.x * blockDim.x + threadIdx.x;
    if (t < E) {
        int c = col[t];
        int r = row[t];
        int rk = atomicAdd(&deg[c], 1);
        if (rk < C) {
            slots[(size_t)c * C + rk] = r;
        } else {
            int o = atomicAdd(ovf_cnt, 1);
            if (o < OVF_CAP) ovf[o] = make_int2(r, c);
        }
    }
    const int stride = gridDim.x * blockDim.x;
    for (int j = t; j < nhalf; j += stride) {
        float2 v = x2[j];
        __hip_bfloat16 bx = __float2bfloat16(v.x);
        __hip_bfloat16 by = __float2bfloat16(v.y);
        uint32 ux = *reinterpret_cast<unsigned short*>(&bx);
        uint32 uy = *reinterpret_cast<unsigned short*>(&by);
        xb[j] = ux | (uy << 16);
    }
}

static inline char* align_up(char* p, size_t a) {
    return (char*)(((uintptr_t)p + (a - 1)) & ~(uintptr_t)(a - 1));
}

extern "C" void kernel_launch(void* const* d_in, const int* in_sizes, int n_in,
                              void* d_out, int out_size, void* d_ws, size_t ws_size,
                              hipStream_t stream) {
    const float* x         = (const float*)d_in[0];
    const float* alpha     = (const float*)d_in[1];
    const float* res_scale = (const float*)d_in[2];
    const int*   ei        = (const int*)d_in[3];

    const int n = in_sizes[0] / D_FEAT;      // 100000
    const int E = in_sizes[3] / 2;           // 1600000
    const int* row = ei;                     // sources
    const int* col = ei + E;                 // targets

    float* out = (float*)d_out;
    const int nhalf = n * (D_FEAT / 2);
    const int C = 32;

    char* p = (char*)d_ws;
    int*    deg     = (int*)p;            p += (size_t)n * 4;
    int*    ovf_cnt = (int*)p;            p += 4;
    int*    cur8    = (int*)p;            p += 32;
    int2*   ovf     = (int2*)p;           p += (size_t)OVF_CAP * 8;
    p = align_up(p, 16);
    uint32* xb      = (uint32*)p;         p += (size_t)n * 128;
    int*    slots   = (int*)p;            p += (size_t)n * C * 4;
    p = align_up(p, 16);
    uint2*  seg     = (uint2*)p;
    const size_t fixed = (size_t)((char*)seg - (char*)d_ws);

    int CAPR = 0;
    if (ws_size > fixed) {
        long long avail = (long long)(ws_size - fixed) / (8 * 8);
        CAPR = (avail > 262144) ? 262144 : (int)avail;
    }

    if (CAPR >= 16384) {
        // zero deg + ovf_cnt + cur8 (contiguous)
        hipMemsetAsync(deg, 0, (size_t)n * 4 + 4 + 32, stream);
        const int B = (E + EB - 1) / EB;
        k_split<<<B, 256, 0, stream>>>(row, col, (const float2*)x, xb, seg, cur8,
                                       deg, slots, ovf, ovf_cnt, nhalf, E, CAPR, C);
        k_place<<<8 * NSUB, 256, 0, stream>>>(seg, cur8, deg, slots, ovf, ovf_cnt,
                                              CAPR, C);
        const long long tt = (long long)n * D_FEAT;
        const int blocks = (int)((tt + 255) / 256);
        k_gather4<<<blocks, 256, 0, stream>>>(xb, (const float4*)x, deg, slots,
                                              alpha, res_scale, (float4*)out, n, C);
        k_ovf<<<64, 256, 0, stream>>>(ovf, ovf_cnt, x, deg, alpha, out);
        return;
    }

    // ---------- fallback: direct scatter build (round-4 path) ----------
    {
        // reuse same layout minus seg; adaptive C if workspace is tiny
        char* q = (char*)d_ws;
        int*    degf    = (int*)q;            q += (size_t)n * 4;
        int*    ovf_cf  = (int*)q;            q += 4;
        q += 32;                               // skip cur8 slot
        int2*   ovff    = (int2*)q;           q += (size_t)OVF_CAP * 8;
        q = align_up(q, 16);
        uint32* xbf     = (uint32*)q;         q += (size_t)n * 128;
        int*    slotsf  = (int*)q;
        const size_t fxd = (size_t)(q - (char*)d_ws);
        int Cf = 0;
        if (ws_size > fxd) {
            size_t c_avail = (ws_size - fxd) / ((size_t)n * 4);
            Cf = (c_avail > 32) ? 32 : (int)c_avail;
        }
        if (Cf < 1) return;
        hipMemsetAsync(degf, 0, (size_t)n * 4 + 4, stream);
        k_prep<<<(E + 255) / 256, 256, 0, stream>>>(
            (const float2*)x, xbf, row, col, degf, slotsf, ovff, ovf_cf,
            nhalf, E, Cf);
        const long long tt = (long long)n * D_FEAT;
        const int blocks = (int)((tt + 255) / 256);
        k_gather4<<<blocks, 256, 0, stream>>>(xbf, (const float4*)x, degf, slotsf,
                                              alpha, res_scale, (float4*)out, n, Cf);
        k_ovf<<<64, 256, 0, stream>>>(ovff, ovf_cf, x, degf, alpha, out);
    }
}

// Round 6
// 182.413 us; speedup vs baseline: 1.3901x; 1.3901x over previous
//
#include <hip/hip_runtime.h>
#include <hip/hip_bf16.h>

#define D_FEAT 64
#define OVF_CAP 65536
#define EB 4096              // edges per scatter block
#define NBMAX 1024           // max buckets (128 nodes each -> n <= 131072)

typedef unsigned int uint32;

__device__ inline float blo(uint32 u) { return __uint_as_float(u << 16); }
__device__ inline float bhi(uint32 u) { return __uint_as_float(u & 0xffff0000u); }
__device__ inline float dinv(int d) { return (d > 0) ? rsqrtf((float)d) : 0.0f; }

// ---- phase 1 (fused): LDS bucket hist -> one global-atomic reservation per
//      (block,bucket) -> placement into CAP-padded segments; fused bf16 cast.
//      1024 threads/block: 391 blocks x 16 waves = 24 waves/CU (round-3 ran
//      4 waves/block and was latency-bound).
__global__ __launch_bounds__(1024) void k_scatter(const int* __restrict__ row,
                                                  const int* __restrict__ col,
                                                  const float2* __restrict__ x2,
                                                  uint32* __restrict__ xb,
                                                  int* __restrict__ deg,
                                                  int* __restrict__ cursor,
                                                  uint32* __restrict__ binned,
                                                  int* __restrict__ slots,
                                                  int2* __restrict__ ovf,
                                                  int* __restrict__ ovf_cnt,
                                                  int nhalf, int E, int nb,
                                                  int CAP, int C) {
    __shared__ int h[NBMAX];
    for (int i = threadIdx.x; i < nb; i += 1024) h[i] = 0;
    __syncthreads();
    const int s = blockIdx.x * EB;
    const int e = (s + EB < E) ? s + EB : E;
    // pass 1: per-block bucket histogram (LDS atomics only)
    for (int i = s + threadIdx.x; i < e; i += 1024)
        atomicAdd(&h[col[i] >> 7], 1);
    __syncthreads();
    // reserve one contiguous slice per non-empty bucket (1 global atomic each)
    for (int k = threadIdx.x; k < nb; k += 1024) {
        int c = h[k];
        if (c) h[k] = atomicAdd(&cursor[k], c);   // h[k] := within-bucket base
    }
    __syncthreads();
    // pass 2: place edges (col re-read is L1/L2-hot)
    for (int i = s + threadIdx.x; i < e; i += 1024) {
        int c = col[i];
        uint32 r = (uint32)row[i];
        int b = c >> 7;
        int pos = atomicAdd(&h[b], 1);            // LDS cursor from reserved base
        if (pos < CAP) {
            binned[(size_t)b * CAP + pos] = (r << 7) | (uint32)(c & 127);
        } else {
            // segment full: exact direct scatter (ranks 0..d0 of node c)
            int rk = atomicAdd(&deg[c], 1);
            if (rk < C) {
                slots[(size_t)c * C + rk] = (int)r;
            } else {
                int o = atomicAdd(ovf_cnt, 1);
                if (o < OVF_CAP) ovf[o] = make_int2((int)r, c);
            }
        }
    }
    // fused bf16 cast, node-major linear (xb[node] = 32 contiguous uint32)
    const int t = blockIdx.x * 1024 + threadIdx.x;
    const int stride = gridDim.x * 1024;
    for (int j = t; j < nhalf; j += stride) {
        float2 v = x2[j];
        __hip_bfloat16 bx = __float2bfloat16(v.x);
        __hip_bfloat16 by = __float2bfloat16(v.y);
        uint32 ux = *reinterpret_cast<unsigned short*>(&bx);
        uint32 uy = *reinterpret_cast<unsigned short*>(&by);
        xb[j] = ux | (uy << 16);
    }
}

// ---- phase 2: per-bucket LDS ranks -> padded slots; fused deg + winv.
//      One block OWNS its 128-node x 128B slot window: every slot line is
//      written by exactly one block, once (the round-4/5 write-amplification
//      lesson). Ranks seeded from deg[] so scatter-overflow edges (ranks
//      0..d0) never collide with binned ranks (d0..).
__global__ __launch_bounds__(512) void k_build(const int* __restrict__ cursor,
                                               const uint32* __restrict__ binned,
                                               int* __restrict__ slots,
                                               int* __restrict__ deg,
                                               float* __restrict__ winv,
                                               int2* __restrict__ ovf,
                                               int* __restrict__ ovf_cnt,
                                               int n, int C, int CAP) {
    __shared__ int cnt[128];
    const int k = blockIdx.x;
    const int base = k << 7;
    if (threadIdx.x < 128) {
        int node = base + threadIdx.x;
        cnt[threadIdx.x] = (node < n) ? deg[node] : 0;   // seed with overflow count
    }
    __syncthreads();
    int tot = cursor[k];
    const int e = (tot < CAP) ? tot : CAP;
    const uint32* seg = binned + (size_t)k * CAP;
    for (int i = threadIdx.x; i < e; i += 512) {
        uint32 pk = seg[i];
        int cl = (int)(pk & 127);
        int r  = (int)(pk >> 7);
        int rk = atomicAdd(&cnt[cl], 1);                 // LDS atomic
        if (rk < C) {
            slots[(size_t)(base + cl) * C + rk] = r;
        } else {
            int o = atomicAdd(ovf_cnt, 1);
            if (o < OVF_CAP) ovf[o] = make_int2(r, base + cl);
        }
    }
    __syncthreads();
    int i = base + threadIdx.x;
    if (threadIdx.x < 128 && i < n) {
        int d = cnt[threadIdx.x];
        deg[i] = d;
        winv[i] = dinv(d);
    }
}

// ---- gather: one wave per node, 4 edges in parallel, 16-edge unroll ----
// (verified body: 60.4 us, ~3.4 TB/s random-128B fetch — do not touch)
__global__ void k_gather4d(const uint32* __restrict__ xb,
                           const float4* __restrict__ x4,
                           const int* __restrict__ deg,
                           const float* __restrict__ winv,
                           const int* __restrict__ slots,
                           const float* __restrict__ alpha_p,
                           const float* __restrict__ rs_p,
                           float4* __restrict__ out4, int n, int C) {
    int wid = (blockIdx.x * blockDim.x + threadIdx.x) >> 6;
    if (wid >= n) return;
    const int lane = threadIdx.x & 63;
    const int q = lane >> 4;
    const int l = lane & 15;
    int d = deg[wid];
    int e = (d < C) ? d : C;
    float4 xr = make_float4(0.f, 0.f, 0.f, 0.f);
    if (q == 0) xr = x4[(size_t)wid * 16 + l];   // hoisted residual load
    const int* sl = slots + (size_t)wid * C;
    float ax = 0.f, ay = 0.f, az = 0.f, aw = 0.f;
    int k = 0;
    for (; k + 16 <= e; k += 16) {
        int s0 = sl[k + q];
        int s1 = sl[k + 4 + q];
        int s2 = sl[k + 8 + q];
        int s3 = sl[k + 12 + q];
        float w0 = winv[s0], w1 = winv[s1], w2 = winv[s2], w3 = winv[s3];
        uint2 p0 = ((const uint2*)(xb + (size_t)s0 * 32))[l];
        uint2 p1 = ((const uint2*)(xb + (size_t)s1 * 32))[l];
        uint2 p2 = ((const uint2*)(xb + (size_t)s2 * 32))[l];
        uint2 p3 = ((const uint2*)(xb + (size_t)s3 * 32))[l];
        ax = fmaf(w0, blo(p0.x), ax); ay = fmaf(w0, bhi(p0.x), ay);
        az = fmaf(w0, blo(p0.y), az); aw = fmaf(w0, bhi(p0.y), aw);
        ax = fmaf(w1, blo(p1.x), ax); ay = fmaf(w1, bhi(p1.x), ay);
        az = fmaf(w1, blo(p1.y), az); aw = fmaf(w1, bhi(p1.y), aw);
        ax = fmaf(w2, blo(p2.x), ax); ay = fmaf(w2, bhi(p2.x), ay);
        az = fmaf(w2, blo(p2.y), az); aw = fmaf(w2, bhi(p2.y), aw);
        ax = fmaf(w3, blo(p3.x), ax); ay = fmaf(w3, bhi(p3.x), ay);
        az = fmaf(w3, blo(p3.y), az); aw = fmaf(w3, bhi(p3.y), aw);
    }
    for (; k < e; k += 4) {
        int kk = k + q;
        if (kk < e) {
            int s0 = sl[kk];
            float w0 = winv[s0];
            uint2 p0 = ((const uint2*)(xb + (size_t)s0 * 32))[l];
            ax = fmaf(w0, blo(p0.x), ax); ay = fmaf(w0, bhi(p0.x), ay);
            az = fmaf(w0, blo(p0.y), az); aw = fmaf(w0, bhi(p0.y), aw);
        }
    }
    ax += __shfl_down(ax, 32, 64); ay += __shfl_down(ay, 32, 64);
    az += __shfl_down(az, 32, 64); aw += __shfl_down(aw, 32, 64);
    ax += __shfl_down(ax, 16, 64); ay += __shfl_down(ay, 16, 64);
    az += __shfl_down(az, 16, 64); aw += __shfl_down(aw, 16, 64);
    if (q == 0) {
        float adw = (*alpha_p) * winv[wid];
        float rs  = *rs_p;
        float4 o;
        o.x = fmaf(adw, ax, rs * xr.x);
        o.y = fmaf(adw, ay, rs * xr.y);
        o.z = fmaf(adw, az, rs * xr.z);
        o.w = fmaf(adw, aw, rs * xr.w);
        out4[(size_t)wid * 16 + l] = o;
    }
}

// ---- overflow fix-up (deg>C only; rare): fp32 exact ----
__global__ void k_ovf(const int2* __restrict__ ovf, const int* __restrict__ cnt_p,
                      const float* __restrict__ x, const float* __restrict__ winv,
                      const float* __restrict__ alpha_p, float* __restrict__ out) {
    int cnt = *cnt_p;
    if (cnt > OVF_CAP) cnt = OVF_CAP;
    if (cnt <= 0) return;
    float a = *alpha_p;
    long long total = (long long)cnt * 64;
    long long stride = (long long)gridDim.x * blockDim.x;
    for (long long idx = blockIdx.x * (long long)blockDim.x + threadIdx.x;
         idx < total; idx += stride) {
        int e = (int)(idx >> 6);
        int f = (int)(idx & 63);
        int2 rc = ovf[e];
        float w = a * winv[rc.x] * winv[rc.y];
        atomicAdd(&out[(size_t)rc.y * D_FEAT + f], w * x[(size_t)rc.x * D_FEAT + f]);
    }
}

// ---- winv table for the fallback path ----
__global__ void k_winv(const int* __restrict__ deg, float* __restrict__ winv, int n) {
    int i = blockIdx.x * blockDim.x + threadIdx.x;
    if (i < n) winv[i] = dinv(deg[i]);
}

// ================= fallback: direct padded-CSR build (round 4) ===============
__global__ __launch_bounds__(256) void k_prep(const float2* __restrict__ x2,
                                              uint32* __restrict__ xb,
                                              const int* __restrict__ row,
                                              const int* __restrict__ col,
                                              int* __restrict__ deg,
                                              int* __restrict__ slots,
                                              int2* __restrict__ ovf,
                                              int* __restrict__ ovf_cnt,
                                              int nhalf, int E, int C) {
    const int t = blockIdx.x * blockDim.x + threadIdx.x;
    if (t < E) {
        int c = col[t];
        int r = row[t];
        int rk = atomicAdd(&deg[c], 1);
        if (rk < C) {
            slots[(size_t)c * C + rk] = r;
        } else {
            int o = atomicAdd(ovf_cnt, 1);
            if (o < OVF_CAP) ovf[o] = make_int2(r, c);
        }
    }
    const int stride = gridDim.x * blockDim.x;
    for (int j = t; j < nhalf; j += stride) {
        float2 v = x2[j];
        __hip_bfloat16 bx = __float2bfloat16(v.x);
        __hip_bfloat16 by = __float2bfloat16(v.y);
        uint32 ux = *reinterpret_cast<unsigned short*>(&bx);
        uint32 uy = *reinterpret_cast<unsigned short*>(&by);
        xb[j] = ux | (uy << 16);
    }
}

static inline char* align_up(char* p, size_t a) {
    return (char*)(((uintptr_t)p + (a - 1)) & ~(uintptr_t)(a - 1));
}

extern "C" void kernel_launch(void* const* d_in, const int* in_sizes, int n_in,
                              void* d_out, int out_size, void* d_ws, size_t ws_size,
                              hipStream_t stream) {
    const float* x         = (const float*)d_in[0];
    const float* alpha     = (const float*)d_in[1];
    const float* res_scale = (const float*)d_in[2];
    const int*   ei        = (const int*)d_in[3];

    const int n = in_sizes[0] / D_FEAT;      // 100000
    const int E = in_sizes[3] / 2;           // 1600000
    const int* row = ei;                     // sources
    const int* col = ei + E;                 // targets

    float* out = (float*)d_out;
    const int nhalf = n * (D_FEAT / 2);
    const int nb = (n + 127) >> 7;           // 128-node buckets (782)
    const int B  = (E + EB - 1) / EB;        // scatter blocks (391)
    const int C  = 32;

    // ---------- reservation multisplit + bucket-exclusive build ----------
    {
        char* p = (char*)d_ws;
        int*    deg     = (int*)p;            p += (size_t)n * 4;
        int*    cursor  = (int*)p;            p += (size_t)nb * 4;
        int*    ovf_cnt = (int*)p;            p += 4;
        float*  winv    = (float*)p;          p += (size_t)n * 4;
        int2*   ovf     = (int2*)p;           p += (size_t)OVF_CAP * 8;
        p = align_up(p, 16);
        uint32* xb      = (uint32*)p;         p += (size_t)n * 128;
        int*    slots   = (int*)p;            p += (size_t)n * C * 4;
        p = align_up(p, 16);
        uint32* binned  = (uint32*)p;
        const size_t fixed = (size_t)((char*)binned - (char*)d_ws);

        int CAP = 0;
        if (ws_size > fixed) {
            long long avail = (long long)(ws_size - fixed) / ((long long)nb * 4);
            CAP = (avail > 4096) ? 4096 : (int)avail;
            CAP &= ~31;
        }
        const bool ok = (CAP >= 1600) && (nb <= NBMAX) && (n <= (NBMAX << 7));
        if (ok) {
            // zero deg + cursor + ovf_cnt (contiguous)
            hipMemsetAsync(deg, 0, (size_t)(n + nb + 1) * 4, stream);
            k_scatter<<<B, 1024, 0, stream>>>(row, col, (const float2*)x, xb,
                                              deg, cursor, binned, slots,
                                              ovf, ovf_cnt, nhalf, E, nb, CAP, C);
            k_build<<<nb, 512, 0, stream>>>(cursor, binned, slots, deg, winv,
                                            ovf, ovf_cnt, n, C, CAP);
            const long long tt = (long long)n * D_FEAT;
            const int blocks = (int)((tt + 255) / 256);
            k_gather4d<<<blocks, 256, 0, stream>>>(xb, (const float4*)x, deg, winv,
                                                   slots, alpha, res_scale,
                                                   (float4*)out, n, C);
            k_ovf<<<64, 256, 0, stream>>>(ovf, ovf_cnt, x, winv, alpha, out);
            return;
        }
    }

    // ---------- fallback: direct scatter build (round-4 path) ----------
    {
        char* q = (char*)d_ws;
        int*    degf    = (int*)q;            q += (size_t)n * 4;
        int*    ovf_cf  = (int*)q;            q += 4;
        float*  winvf   = (float*)q;          q += (size_t)n * 4;
        int2*   ovff    = (int2*)q;           q += (size_t)OVF_CAP * 8;
        q = align_up(q, 16);
        uint32* xbf     = (uint32*)q;         q += (size_t)n * 128;
        int*    slotsf  = (int*)q;
        const size_t fxd = (size_t)(q - (char*)d_ws);
        int Cf = 0;
        if (ws_size > fxd) {
            size_t c_avail = (ws_size - fxd) / ((size_t)n * 4);
            Cf = (c_avail > 32) ? 32 : (int)c_avail;
        }
        if (Cf < 1) return;
        hipMemsetAsync(degf, 0, (size_t)n * 4 + 4, stream);
        k_prep<<<(E + 255) / 256, 256, 0, stream>>>(
            (const float2*)x, xbf, row, col, degf, slotsf, ovff, ovf_cf,
            nhalf, E, Cf);
        k_winv<<<(n + 255) / 256, 256, 0, stream>>>(degf, winvf, n);
        const long long tt = (long long)n * D_FEAT;
        const int blocks = (int)((tt + 255) / 256);
        k_gather4d<<<blocks, 256, 0, stream>>>(xbf, (const float4*)x, degf, winvf,
                                               slotsf, alpha, res_scale,
                                               (float4*)out, n, Cf);
        k_ovf<<<64, 256, 0, stream>>>(ovff, ovf_cf, x, winvf, alpha, out);
    }
}